// Round 12
// baseline (165.467 us; speedup 1.0000x reference)
//
#include <hip/hip_runtime.h>

typedef float f32x4 __attribute__((ext_vector_type(4)));
typedef short bf16x8 __attribute__((ext_vector_type(8)));

#define NB 8
#define NH 16
#define NSEQ 1024
#define NP 64
#define NKV 1088
#define NC 1024
#define NHD 64
#define BHSZ 69632  // per-(b,h) K/V fragment-packed size = 1088*64

__device__ __forceinline__ unsigned short f2bf(float f) {
  unsigned int u = __builtin_bit_cast(unsigned int, f);
  u += 0x7fffu + ((u >> 16) & 1u);  // RNE
  return (unsigned short)(u >> 16);
}

__device__ __forceinline__ f32x4 mfma16(bf16x8 a, bf16x8 b, f32x4 c) {
  return __builtin_amdgcn_mfma_f32_16x16x32_bf16(a, b, c, 0, 0, 0);
}

// fragment-packed address (element granularity) for a row-major [R][1024] matrix
// (GEMM A/B operands). row = panel*128 + wr*64 + m*16 + lr ; k = t*64 + kk*32 + lg*8 + e
__device__ __forceinline__ size_t fa_elem(int r, int k) {
  return (size_t)(r >> 7) * 131072 + (size_t)(k >> 6) * 8192 + ((r >> 6) & 1) * 4096 +
         ((k >> 5) & 1) * 2048 + ((r >> 4) & 3) * 512 + (((k >> 3) & 3) * 16 + (r & 15)) * 8 +
         (k & 7);
}

// ---------------- fused pack kernel ----------------
__device__ __forceinline__ void fragpack_chunk(const float* __restrict__ src,
                                               unsigned short* __restrict__ dst, int c) {
  const int lane = c & 63, m = (c >> 6) & 3, kk = (c >> 8) & 1, wr = (c >> 9) & 1,
            t = (c >> 10) & 15, panel = c >> 14;
  const int row = panel * 128 + wr * 64 + m * 16 + (lane & 15);
  const int k = t * 64 + kk * 32 + (lane >> 4) * 8;
  const float* s = src + (size_t)row * 1024 + k;
  const float4 v0 = *(const float4*)s;
  const float4 v1 = *(const float4*)(s + 4);
  ushort4 o0, o1;
  o0.x = f2bf(v0.x); o0.y = f2bf(v0.y); o0.z = f2bf(v0.z); o0.w = f2bf(v0.w);
  o1.x = f2bf(v1.x); o1.y = f2bf(v1.y); o1.z = f2bf(v1.z); o1.w = f2bf(v1.w);
  *(ushort4*)(dst + (size_t)c * 8) = o0;
  *(ushort4*)(dst + (size_t)c * 8 + 4) = o1;
}

__global__ void pack_fused(const float* __restrict__ x, const float* __restrict__ wq,
                           const float* __restrict__ wp, const float* __restrict__ prompt,
                           unsigned short* __restrict__ xd, unsigned short* __restrict__ wqd,
                           unsigned short* __restrict__ wpd, unsigned short* __restrict__ Kf,
                           unsigned short* __restrict__ Vf, const float* __restrict__ alpha) {
  int gid = blockIdx.x * 256 + threadIdx.x;
  if (gid < 1048576) {                       // x: 8192x1024
    fragpack_chunk(x, xd, gid);
  } else if (gid < 1441792) {                // Wqkv: 3072x1024
    fragpack_chunk(wq, wqd, gid - 1048576);
  } else if (gid < 1572864) {                // Wproj: 1024x1024
    fragpack_chunk(wp, wpd, gid - 1441792);
  } else {                                   // prompt prefix (t=0 tiles of K/V frag layout)
    int i = gid - 1572864;                   // 131072
    float a = alpha[0];
    int d4 = i & 15, p = (i >> 4) & 63, h = (i >> 10) & 15, b = i >> 14;
    const int bh = b * 16 + h;
    const int d0 = d4 * 4;
    const float4 kv4 = *(const float4*)(prompt + ((((size_t)(b * 2 + 0) * NP + p) * NH + h) * NHD + d0));
    {
      const int mk = p >> 4, lrk = p & 15, kk = d0 >> 5, lg = (d0 >> 3) & 3, e0 = d0 & 7;
      unsigned short* kd = Kf + (size_t)bh * BHSZ + ((mk * 2 + kk) * 4 + lg) * 128 + lrk * 8 + e0;
      kd[0] = f2bf(kv4.x * a); kd[1] = f2bf(kv4.y * a);
      kd[2] = f2bf(kv4.z * a); kd[3] = f2bf(kv4.w * a);
    }
    const float4 vv4 = *(const float4*)(prompt + ((((size_t)(b * 2 + 1) * NP + p) * NH + h) * NHD + d0));
    {
      const int df = d0 >> 4, kk = p >> 5, lg = (p >> 3) & 3, e = p & 7;
      unsigned short* vd = Vf + (size_t)bh * BHSZ + ((df * 2 + kk) * 4 + lg) * 128 + e;
      vd[((d0 + 0) & 15) * 8] = f2bf(vv4.x * a);
      vd[((d0 + 1) & 15) * 8] = f2bf(vv4.y * a);
      vd[((d0 + 2) & 15) * 8] = f2bf(vv4.z * a);
      vd[((d0 + 3) & 15) * 8] = f2bf(vv4.w * a);
    }
  }
}

// ---------------- direct-streaming GEMM: inline-asm 2-deep load pipeline ----------
// asm volatile global_load_dwordx4 + counted vmcnt(16) -> 16 loads structurally in
// flight across each 32-MFMA cluster (volatile asm ordering; compiler cannot sink).
// sched_barrier(0) after each waitcnt (rule #18) stops MFMA hoisting above it.
template <int MODE>
__global__ __launch_bounds__(256, 2)
void gemm_direct(const unsigned short* __restrict__ Af, const unsigned short* __restrict__ Bf,
                 unsigned short* __restrict__ Qg, unsigned short* __restrict__ Kf,
                 unsigned short* __restrict__ Vf,
                 const float* __restrict__ alphap, const float* __restrict__ halfp,
                 float* __restrict__ Cout, const float* __restrict__ bias) {
  const int tid = threadIdx.x, lane = tid & 63, wv = tid >> 6;
  const int wr = wv >> 1, wc = wv & 1;
  const int lg = lane >> 4, lr = lane & 15;
  const int bx = blockIdx.x, by = blockIdx.y;

  // byte voffsets into frag-packed operands (32-bit; matrices < 4GB)
  unsigned int vA0 = (unsigned)(bx * 131072 + wr * 4096 + lane * 8) * 2;
  unsigned int vA1 = vA0 + 4096;
  unsigned int vB0 = (unsigned)(by * 131072 + wc * 4096 + lane * 8) * 2;
  unsigned int vB1 = vB0 + 4096;

  f32x4 acc[4][4] = {};
  bf16x8 aE[2][4], bE[2][4], aO[2][4], bO[2][4];

#define GLD(dst, voff, base, imm)                                              \
  asm volatile("global_load_dwordx4 %0, %1, %2 offset:" #imm                   \
               : "=v"(dst) : "v"(voff), "s"(base))

#define ISSUE_T(aX, bX)                                                        \
  do {                                                                         \
    GLD(aX[0][0], vA0, Af, 0);                                                 \
    GLD(aX[0][1], vA0, Af, 1024);                                              \
    GLD(aX[0][2], vA0, Af, 2048);                                              \
    GLD(aX[0][3], vA0, Af, 3072);                                              \
    GLD(aX[1][0], vA1, Af, 0);                                                 \
    GLD(aX[1][1], vA1, Af, 1024);                                              \
    GLD(aX[1][2], vA1, Af, 2048);                                              \
    GLD(aX[1][3], vA1, Af, 3072);                                              \
    GLD(bX[0][0], vB0, Bf, 0);                                                 \
    GLD(bX[0][1], vB0, Bf, 1024);                                              \
    GLD(bX[0][2], vB0, Bf, 2048);                                              \
    GLD(bX[0][3], vB0, Bf, 3072);                                              \
    GLD(bX[1][0], vB1, Bf, 0);                                                 \
    GLD(bX[1][1], vB1, Bf, 1024);                                              \
    GLD(bX[1][2], vB1, Bf, 2048);                                              \
    GLD(bX[1][3], vB1, Bf, 3072);                                              \
    vA0 += 16384; vA1 += 16384; vB0 += 16384; vB1 += 16384;                    \
  } while (0)

#define MFMA_T(aX, bX)                                                         \
  do {                                                                         \
    __builtin_amdgcn_s_setprio(1);                                             \
    _Pragma("unroll") for (int kk = 0; kk < 2; ++kk)                           \
    _Pragma("unroll") for (int m = 0; m < 4; ++m)                              \
    _Pragma("unroll") for (int n = 0; n < 4; ++n)                              \
        acc[m][n] = mfma16(aX[kk][m], bX[kk][n], acc[m][n]);                   \
    __builtin_amdgcn_s_setprio(0);                                             \
  } while (0)

  ISSUE_T(aE, bE);  // tile 0
  ISSUE_T(aO, bO);  // tile 1
#pragma unroll
  for (int t = 0; t < 16; ++t) {
    if (t < 15) asm volatile("s_waitcnt vmcnt(16)" ::: "memory");  // tile t landed
    else        asm volatile("s_waitcnt vmcnt(0)" ::: "memory");
    __builtin_amdgcn_sched_barrier(0);
    if ((t & 1) == 0) {
      MFMA_T(aE, bE);
      if (t + 2 < 16) ISSUE_T(aE, bE);
    } else {
      MFMA_T(aO, bO);
      if (t + 2 < 16) ISSUE_T(aO, bO);
    }
  }
#undef GLD
#undef ISSUE_T
#undef MFMA_T

  if constexpr (MODE == 0) {
    const int slot = (by * 128) >> 10;
    const int csIn = (by * 128) & 1023;
    // Q gets softmax scale folded in base-2 domain: 0.125 * log2(e)
    const float sc = (slot == 0) ? 0.18033688011112042f : (alphap[0] * halfp[0]);
#pragma unroll
    for (int m = 0; m < 4; ++m) {
      const int grow0 = bx * 128 + wr * 64 + m * 16 + lg * 4;
#pragma unroll
      for (int n = 0; n < 4; ++n) {
        const int gcol = csIn + wc * 64 + n * 16 + lr;
        const int h = gcol >> 6, d = gcol & 63;
#pragma unroll
        for (int j = 0; j < 4; ++j) {
          const int grow = grow0 + j;
          const int b = grow >> 10, nn = grow & 1023;
          const int bh = b * 16 + h;
          const unsigned short u = f2bf(acc[m][n][j] * sc);
          if (slot == 0) {
            Qg[((size_t)bh * NSEQ + nn) * NHD + d] = u;
          } else if (slot == 1) {
            const int kv = NP + nn;
            const int t = kv >> 6, mk = (kv >> 4) & 3, lrk = kv & 15;
            const int kkk = d >> 5, lgk = (d >> 3) & 3, e = d & 7;
            Kf[(size_t)bh * BHSZ + (size_t)((t * 4 + mk) * 2 + kkk) * 512 + (lgk * 16 + lrk) * 8 + e] = u;
          } else {
            const int kv = NP + nn;
            const int t = kv >> 6, kkv = (kv >> 5) & 1, lgv = (kv >> 3) & 3, e = kv & 7;
            const int df = d >> 4, lrv = d & 15;
            Vf[(size_t)bh * BHSZ + (size_t)((t * 4 + df) * 2 + kkv) * 512 + (lgv * 16 + lrv) * 8 + e] = u;
          }
        }
      }
    }
  } else {
#pragma unroll
    for (int m = 0; m < 4; ++m) {
      const int grow0 = bx * 128 + wr * 64 + m * 16 + lg * 4;
#pragma unroll
      for (int n = 0; n < 4; ++n) {
        const int gcol = by * 128 + wc * 64 + n * 16 + lr;
        const float bb = bias[gcol];
#pragma unroll
        for (int j = 0; j < 4; ++j)
          Cout[(size_t)(grow0 + j) * NC + gcol] = acc[m][n][j] + bb;
      }
    }
  }
}

// ---------------- flash attention: barrier-free, frag-direct K/V streaming ----------
__global__ __launch_bounds__(256, 3)
void attn_fwd(const unsigned short* __restrict__ Qg, const unsigned short* __restrict__ Kf,
              const unsigned short* __restrict__ Vf, unsigned short* __restrict__ Oat) {
  __shared__ __align__(16) unsigned short Plds[4 * 32 * 64];
  const int tid = threadIdx.x, lane = tid & 63, wv = tid >> 6;
  const int bh = blockIdx.x & 127;
  const int q0 = (blockIdx.x >> 7) * 128;
  const int lg = lane >> 4, lr = lane & 15;

  bf16x8 bq[2][2];
#pragma unroll
  for (int nq = 0; nq < 2; ++nq)
#pragma unroll
    for (int kk = 0; kk < 2; ++kk)
      bq[nq][kk] = *(const bf16x8*)(Qg + ((size_t)bh * NSEQ + q0 + wv * 32 + nq * 16 + lr) * NHD + kk * 32 + lg * 8);

  f32x4 oac[2][4] = {};
  float mrun[2] = {-1e30f, -1e30f};
  float lrun[2] = {0.f, 0.f};

  const unsigned short* Kb = Kf + (size_t)bh * BHSZ + lane * 8;
  const unsigned short* Vb = Vf + (size_t)bh * BHSZ + lane * 8;
  unsigned short* Pw = Plds + wv * 2048;

  for (int t = 0; t < 17; ++t) {
    bf16x8 ak[4][2];
#pragma unroll
    for (int mk = 0; mk < 4; ++mk)
#pragma unroll
      for (int kk = 0; kk < 2; ++kk)
        ak[mk][kk] = *(const bf16x8*)(Kb + (size_t)((t * 4 + mk) * 2 + kk) * 512);

    f32x4 sa[4][2] = {};
    __builtin_amdgcn_s_setprio(1);
#pragma unroll
    for (int kk = 0; kk < 2; ++kk)
#pragma unroll
      for (int mk = 0; mk < 4; ++mk)
#pragma unroll
        for (int nq = 0; nq < 2; ++nq)
          sa[mk][nq] = mfma16(ak[mk][kk], bq[nq][kk], sa[mk][nq]);
    __builtin_amdgcn_s_setprio(0);

    bf16x8 bv[4][2];
#pragma unroll
    for (int df = 0; df < 4; ++df)
#pragma unroll
      for (int kk = 0; kk < 2; ++kk)
        bv[df][kk] = *(const bf16x8*)(Vb + (size_t)((t * 4 + df) * 2 + kk) * 512);

    float tmx[2];
#pragma unroll
    for (int nq = 0; nq < 2; ++nq) {
      f32x4 m4 = sa[0][nq];
#pragma unroll
      for (int mk = 1; mk < 4; ++mk)
#pragma unroll
        for (int j = 0; j < 4; ++j) m4[j] = fmaxf(m4[j], sa[mk][nq][j]);
      float tm = fmaxf(fmaxf(m4[0], m4[1]), fmaxf(m4[2], m4[3]));
      tm = fmaxf(tm, __shfl_xor(tm, 16));
      tm = fmaxf(tm, __shfl_xor(tm, 32));
      tmx[nq] = tm;
    }
    const bool upd = !__all((tmx[0] <= mrun[0] + 8.f) && (tmx[1] <= mrun[1] + 8.f));
    if (upd) {
      const float nm0 = fmaxf(mrun[0], tmx[0]);
      const float nm1 = fmaxf(mrun[1], tmx[1]);
      const float e0 = __builtin_amdgcn_exp2f(mrun[0] - nm0);
      const float e1 = __builtin_amdgcn_exp2f(mrun[1] - nm1);
      mrun[0] = nm0; mrun[1] = nm1;
      lrun[0] *= e0; lrun[1] *= e1;
#pragma unroll
      for (int m = 0; m < 2; ++m)
#pragma unroll
        for (int j = 0; j < 4; ++j) {
          const float fe = __shfl(m ? e1 : e0, lg * 4 + j, 16);
#pragma unroll
          for (int df = 0; df < 4; ++df) oac[m][df][j] *= fe;
        }
    }
#pragma unroll
    for (int nq = 0; nq < 2; ++nq) {
#pragma unroll
      for (int mk = 0; mk < 4; ++mk)
#pragma unroll
        for (int j = 0; j < 4; ++j)
          sa[mk][nq][j] = __builtin_amdgcn_exp2f(sa[mk][nq][j] - mrun[nq]);
      f32x4 s4 = sa[0][nq];
#pragma unroll
      for (int mk = 1; mk < 4; ++mk)
#pragma unroll
        for (int j = 0; j < 4; ++j) s4[j] += sa[mk][nq][j];
      float s = (s4[0] + s4[1]) + (s4[2] + s4[3]);
      s += __shfl_xor(s, 16);
      s += __shfl_xor(s, 32);
      lrun[nq] += s;
      const int q = nq * 16 + lr;
#pragma unroll
      for (int mk = 0; mk < 4; ++mk) {
        const int c = mk * 2 + (lg >> 1);
        uint2 uu;
        uu.x = (unsigned)f2bf(sa[mk][nq][0]) | ((unsigned)f2bf(sa[mk][nq][1]) << 16);
        uu.y = (unsigned)f2bf(sa[mk][nq][2]) | ((unsigned)f2bf(sa[mk][nq][3]) << 16);
        *(uint2*)(Pw + q * 64 + ((c ^ (q & 7)) << 3) + (lg & 1) * 4) = uu;
      }
    }

    __builtin_amdgcn_s_setprio(1);
#pragma unroll
    for (int kk = 0; kk < 2; ++kk) {
      bf16x8 ap[2];
#pragma unroll
      for (int m = 0; m < 2; ++m) {
        const int q = m * 16 + lr;
        const int pos = (kk * 4 + lg) ^ (q & 7);
        ap[m] = *(const bf16x8*)(Pw + q * 64 + pos * 8);
      }
#pragma unroll
      for (int m = 0; m < 2; ++m)
#pragma unroll
        for (int df = 0; df < 4; ++df)
          oac[m][df] = mfma16(ap[m], bv[df][kk], oac[m][df]);
    }
    __builtin_amdgcn_s_setprio(0);
  }

  // epilogue: write O fragment-packed (proj-A layout) so gemm_direct<1> streams it
  const int bidx = bh >> 4, h = bh & 15;
  const float l0 = 1.f / lrun[0], l1 = 1.f / lrun[1];
#pragma unroll
  for (int m = 0; m < 2; ++m) {
#pragma unroll
    for (int j = 0; j < 4; ++j) {
      const float fi = __shfl(m ? l1 : l0, lg * 4 + j, 16);
      const int grow = bidx * NSEQ + q0 + wv * 32 + m * 16 + lg * 4 + j;
#pragma unroll
      for (int df = 0; df < 4; ++df) {
        const int col = h * 64 + df * 16 + lr;
        Oat[fa_elem(grow, col)] = f2bf(oac[m][df][j] * fi);
      }
    }
  }
}

// ---------------- launch ----------------
extern "C" void kernel_launch(void* const* d_in, const int* in_sizes, int n_in,
                              void* d_out, int out_size, void* d_ws, size_t ws_size,
                              hipStream_t stream) {
  const float* x      = (const float*)d_in[0];
  const float* prompt = (const float*)d_in[1];
  const float* alpha  = (const float*)d_in[2];
  const float* halfa  = (const float*)d_in[3];
  const float* Wqkv   = (const float*)d_in[4];
  const float* Wproj  = (const float*)d_in[5];
  const float* bproj  = (const float*)d_in[6];
  float* out = (float*)d_out;

  unsigned short* ws    = (unsigned short*)d_ws;
  unsigned short* x_bf  = ws;                                  // frag-packed
  unsigned short* w_bf  = x_bf + (size_t)8192 * 1024;          // frag-packed
  unsigned short* wp_bf = w_bf + (size_t)3072 * 1024;          // frag-packed
  unsigned short* Qg    = wp_bf + (size_t)1024 * 1024;         // row-major
  unsigned short* Kf    = Qg + (size_t)NB * NH * NSEQ * NHD;   // attn-frag-packed
  unsigned short* Vf    = Kf + (size_t)128 * BHSZ;             // attn-frag-packed
  unsigned short* Oat   = Vf + (size_t)128 * BHSZ;             // frag-packed

  pack_fused<<<6656, 256, 0, stream>>>(x, Wqkv, Wproj, prompt, x_bf, w_bf, wp_bf,
                                       Kf, Vf, alpha);

  // QKV: M=8192 N=3072 -> 64 x 24 of 128^2, asm-pipelined direct streaming
  gemm_direct<0><<<dim3(64, 24), 256, 0, stream>>>(x_bf, w_bf, Qg, Kf, Vf, alpha, halfa,
                                                   nullptr, nullptr);
  attn_fwd<<<1024, 256, 0, stream>>>(Qg, Kf, Vf, Oat);
  // proj: M=8192 N=1024 -> 64 x 8 of 128^2, asm-pipelined direct streaming
  gemm_direct<1><<<dim3(64, 8), 256, 0, stream>>>(Oat, wp_bf, nullptr, nullptr, nullptr,
                                                  nullptr, nullptr, out, bproj);
}